// Round 5
// baseline (240.665 us; speedup 1.0000x reference)
//
#include <hip/hip_runtime.h>
#include <hip/hip_bf16.h>
#include <math.h>

// Problem constants (B=2, C=256, H=W=64, Co=256, 3x3, stride1, pad1)
#define BB 2
#define CC 256
#define HH 64
#define WW 64
#define COo 256
#define HWs 4096
#define K2 9
#define CK 2304   // C*9

typedef __attribute__((ext_vector_type(4))) float floatx4;
typedef __attribute__((ext_vector_type(8))) short shortx8;   // 8 bf16 = 4 VGPRs

// ---- workspace layout (float units) ----
// P: convA partials fp16 [cs 2][b 2][pix 4096][27] = 442368 halves = 221184 f
#define O_P     0
#define O_WBF   221184     // reg_w bf16 [co][ck] = 589824 bf16 = 294912 f
#define O_WPK   516096     // convA weights [g][cs][tap][kcl 4][nf 2][lane][8] = 147456 bf16
#define O_A     589824     // A matrix bf16 [pix 8192][ck 2304] = 9437184 f
// total = 10,027,008 floats = 40.1 MB

__device__ __forceinline__ void gll16(const __hip_bfloat16* g, __hip_bfloat16* l) {
    __builtin_amdgcn_global_load_lds(
        (const __attribute__((address_space(1))) unsigned int*)g,
        (__attribute__((address_space(3))) unsigned int*)l, 16, 0, 0);
}

__device__ __forceinline__ short f2bf(float v) {
    __hip_bfloat16 h = __float2bfloat16(v);
    return *reinterpret_cast<short*>(&h);
}

// ---------------------------------------------------------------------------
// K0: pack weights.
//  Wbf[co*2304+ck] = bf16(reg_w) (cast-copy, natural layout)
//  Wpk: convA weights: [g 2][cs 2][tap 9][kcl 4][nf 2][lane 64][j 8]
//   c = cs*128 + kcl*32 + (lane>>4)*8 + j, n = nf*16 + (lane&15)
//   g=0: n<18 -> off_w[n][c][tap]; g=1: n<9 -> mod_w[n][c][tap]; else 0
// ---------------------------------------------------------------------------
__global__ __launch_bounds__(256) void pack_kernel(
    const float* __restrict__ reg_w,
    const float* __restrict__ off_w,
    const float* __restrict__ mod_w,
    __hip_bfloat16* __restrict__ Wbf,
    __hip_bfloat16* __restrict__ Wpk)
{
    int idx = blockIdx.x * 256 + threadIdx.x;      // grid covers CK*COo = 589824
    if (idx < CK * COo) {
        Wbf[idx] = __float2bfloat16(reg_w[idx]);
    }
    if (idx < 147456) {
        int g    = idx / 73728;
        int rem  = idx % 73728;
        int cs   = rem / 36864;
        int r2   = rem % 36864;
        int tap  = r2 / 4096;
        int r3   = r2 % 4096;
        int kcl  = r3 >> 10;
        int r4   = r3 & 1023;
        int nf   = r4 >> 9;
        int r5   = r4 & 511;
        int lane = r5 >> 3;
        int j    = r5 & 7;
        int c    = cs * 128 + kcl * 32 + (lane >> 4) * 8 + j;
        int n    = nf * 16 + (lane & 15);
        float v = 0.f;
        if (g == 0) { if (n < 18) v = off_w[((size_t)n * CC + c) * 9 + tap]; }
        else        { if (n < 9)  v = mod_w[((size_t)n * CC + c) * 9 + tap]; }
        Wpk[idx] = __float2bfloat16(v);
    }
}

// ---------------------------------------------------------------------------
// K1: offset + modulator convs via MFMA, channel-split x2, fp16 partials.
// grid = 512: blk = ((b*2+g)*2 + cs)*64 + r.
// Block weight slice = 36864 bf16 = 4608 16B-chunks, staged via
// global_load_lds (18 chunks/thread — R4 bug was 9/thread = half staged).
// ---------------------------------------------------------------------------
__global__ __launch_bounds__(256) void convA_kernel(
    const float* __restrict__ x,
    const float* __restrict__ residual,
    const __hip_bfloat16* __restrict__ Wpk,
    _Float16* __restrict__ P)
{
    int blk = blockIdx.x;
    int r  = blk & 63;
    int cs = (blk >> 6) & 1;
    int g  = (blk >> 7) & 1;
    int b  = blk >> 8;
    int t = threadIdx.x;
    int lane = t & 63;
    int w = t >> 6;
    int ln = lane & 15;
    int quad = lane >> 4;

    __shared__ __hip_bfloat16 Ls[3 * 64 * 64];     // x-tile, swizzled (24 KB)
    __shared__ __hip_bfloat16 Wl[9 * 4 * 2 * 512]; // weight slice (72 KB)

    const float* src = (g ? x : residual) + (size_t)b * CC * HWs;

    // stage this block's weight slice: 4608 16B chunks, 18 per thread
    const __hip_bfloat16* wsrc = Wpk + (size_t)(g * 2 + cs) * 36864;
#pragma unroll
    for (int i = 0; i < 18; ++i) {
        int chunk = i * 256 + t;
        gll16(wsrc + chunk * 8, &Wl[0] + chunk * 8);
    }

    floatx4 acc[2];
    acc[0] = (floatx4){0.f, 0.f, 0.f, 0.f};
    acc[1] = (floatx4){0.f, 0.f, 0.f, 0.f};

    int col = t & 63;
    int q = t >> 6;

    for (int st = 0; st < 2; ++st) {       // two 64-channel stagings
        __syncthreads();
#pragma unroll
        for (int i = 0; i < 6; ++i) {
            int p = q * 6 + i;             // 0..23
            int row = p >> 3;              // 0..2
            int cgp = p & 7;               // c-chunk of 8
            int rimg = r + row - 1;
            bool rv = (rimg >= 0) && (rimg < HH);
            const float* sp = src + (size_t)(cs * 128 + st * 64 + cgp * 8) * HWs
                              + rimg * WW + col;
            shortx8 pk;
#pragma unroll
            for (int jc = 0; jc < 8; ++jc)
                pk[jc] = f2bf(rv ? sp[(size_t)jc * HWs] : 0.f);
            int colIdx = row * 64 + col;
            int pos = cgp ^ (colIdx & 7);
            *(shortx8*)&Ls[colIdx * 64 + pos * 8] = pk;
        }
        __syncthreads();                   // drains weight DMA too (st==0)
#pragma unroll
        for (int tap = 0; tap < 9; ++tap) {
            int ky = tap / 3;
            int kx = tap % 3;
            int colA = w * 16 + ln + kx - 1;
            bool cv = (colA >= 0) && (colA < WW);
            int colC = cv ? colA : 0;
            int colIdx = ky * 64 + colC;
#pragma unroll
            for (int kh = 0; kh < 2; ++kh) {
                int chunk = kh * 4 + quad;
                int pos = chunk ^ (colIdx & 7);
                shortx8 afr = *(const shortx8*)&Ls[colIdx * 64 + pos * 8];
                if (!cv) {
                    shortx8 zf = {0,0,0,0,0,0,0,0};
                    afr = zf;
                }
                int kcl = st * 2 + kh;
                const __hip_bfloat16* wp = &Wl[(((tap * 4 + kcl) * 2) * 64 + lane) * 8];
                shortx8 b0 = *(const shortx8*)wp;
                shortx8 b1 = *(const shortx8*)(wp + 512);
                acc[0] = __builtin_amdgcn_mfma_f32_16x16x32_bf16(afr, b0, acc[0], 0, 0, 0);
                acc[1] = __builtin_amdgcn_mfma_f32_16x16x32_bf16(afr, b1, acc[1], 0, 0, 0);
            }
        }
    }

    // epilogue: C/D layout col=lane&15 (=n), row=quad*4+reg (=pixel)
    // P[cs][b][pix][27]: g=0 -> n 0..17, g=1 -> n 18..26 (disjoint, no race)
#pragma unroll
    for (int nf = 0; nf < 2; ++nf) {
        int n0 = nf * 16 + ln;
        int n_eff = g ? (18 + n0) : n0;
        bool valid = g ? (n0 < 9) : (n0 < 18);
#pragma unroll
        for (int i2 = 0; i2 < 4; ++i2) {
            int pix = r * 64 + w * 16 + quad * 4 + i2;
            if (valid)
                P[((size_t)(cs * 2 + b) * 4096 + pix) * 27 + n_eff] =
                    (_Float16)acc[nf][i2];
        }
    }
}

// ---------------------------------------------------------------------------
// K2: deformable gather -> bf16 A matrix [pix][ck].
// grid = B*H*16 (c-chunk of 16); block 256 = (wo 64) x (cg 4), 4 chan each.
// Partial-sum + bias + sigmoid fused into precompute. s_a transposed [ck][wo]
// (conflict-free lane-major writes); writeout transposes to coalesced 16B.
// ---------------------------------------------------------------------------
__global__ __launch_bounds__(256) void gather_kernel(
    const float* __restrict__ x,
    const _Float16* __restrict__ P,
    const float* __restrict__ off_b,
    const float* __restrict__ mod_b,
    __hip_bfloat16* __restrict__ A)
{
    int blk = blockIdx.x;            // ((b*64 + ho)*16 + cc)
    int cc = blk & 15;
    int ho = (blk >> 4) & 63;
    int b  = blk >> 10;
    int t  = threadIdx.x;
    int wo = t & 63;
    int cg = t >> 6;

    __shared__ int   s_idx[4][K2][64];
    __shared__ float s_w  [4][K2][64];
    __shared__ short s_a[144 * 66];   // [ck_local][wo], pitch 66

    // ---- bilinear precompute: sum 2 partials + bias, sigmoid, corners ----
    for (int u = t; u < K2 * 64; u += 256) {
        int k = u >> 6;
        int wv = u & 63;
        int pix = ho * 64 + wv;
        size_t p0 = ((size_t)(0 + b) * 4096 + pix) * 27;
        size_t p1 = ((size_t)(2 + b) * 4096 + pix) * 27;
        float dy = (float)P[p0 + 2 * k] + (float)P[p1 + 2 * k] + off_b[2 * k];
        float dx = (float)P[p0 + 2 * k + 1] + (float)P[p1 + 2 * k + 1] + off_b[2 * k + 1];
        float z  = (float)P[p0 + 18 + k] + (float)P[p1 + 18 + k] + mod_b[k];
        float m  = 2.f / (1.f + __expf(-z));
        float py = (float)(ho - 1 + k / 3) + dy;
        float px = (float)(wv - 1 + k % 3) + dx;
        float y0f = floorf(py), x0f = floorf(px);
        float wy1 = py - y0f, wx1 = px - x0f;
        float wy0 = 1.f - wy1, wx0 = 1.f - wx1;
        int y0 = (int)y0f, x0 = (int)x0f;
#pragma unroll
        for (int j = 0; j < 4; ++j) {
            int yy = y0 + (j >> 1);
            int xx = x0 + (j & 1);
            float wj = ((j == 0) ? wy0 * wx0 :
                        (j == 1) ? wy0 * wx1 :
                        (j == 2) ? wy1 * wx0 : wy1 * wx1) * m;
            bool valid = (yy >= 0) && (yy < HH) && (xx >= 0) && (xx < WW);
            s_idx[j][k][wv] = valid ? (yy * WW + xx) : 0;
            s_w  [j][k][wv] = valid ? wj : 0.f;
        }
    }
    __syncthreads();

    // ---- gather: k-outer, 4 channels inner; transposed s_a writes ----
    const float* xb = x + ((size_t)b * CC + cc * 16) * HWs;
#pragma unroll
    for (int k = 0; k < K2; ++k) {
        int   i0 = s_idx[0][k][wo], i1 = s_idx[1][k][wo];
        int   i2 = s_idx[2][k][wo], i3 = s_idx[3][k][wo];
        float w0 = s_w[0][k][wo], w1 = s_w[1][k][wo];
        float w2 = s_w[2][k][wo], w3 = s_w[3][k][wo];
#pragma unroll
        for (int j = 0; j < 4; ++j) {
            int cl = cg * 4 + j;
            const float* xc = xb + (size_t)cl * HWs;
            float v = w0 * xc[i0] + w1 * xc[i1] + w2 * xc[i2] + w3 * xc[i3];
            s_a[(cl * 9 + k) * 66 + wo] = f2bf(v);
        }
    }
    __syncthreads();

    // ---- writeout: transpose from s_a, 16B coalesced global stores ----
    int pixbase = (b * 64 + ho) * 64;
    for (int id = t; id < 1152; id += 256) {     // 64 rows x 18 chunks
        int rr  = id / 18;
        int ch8 = id % 18;
        shortx8 pk;
#pragma unroll
        for (int jj = 0; jj < 8; ++jj)
            pk[jj] = s_a[(ch8 * 8 + jj) * 66 + rr];
        *(shortx8*)(A + (size_t)(pixbase + rr) * CK + cc * 144 + ch8 * 8) = pk;
    }
}

// ---------------------------------------------------------------------------
// K3: bf16 MFMA GEMM  C[8192][256] = A[8192][2304] x Wbf^T, out NCHW.
// grid = 64 Mtiles x 4 Ntiles; tile 128M x 64N, BK=32. Double-buffered
// global_load_lds: one barrier per K-iter, prefetch overlaps MFMA.
// ---------------------------------------------------------------------------
__global__ __launch_bounds__(256) void gemm_kernel(
    const __hip_bfloat16* __restrict__ A,
    const __hip_bfloat16* __restrict__ Wbf,
    float* __restrict__ out)
{
    int blk = blockIdx.x;
    int mt = blk >> 2;          // pix base mt*128
    int nt = blk & 3;           // co base nt*64
    int t  = threadIdx.x;
    int lane = t & 63;
    int w    = t >> 6;
    int quad = lane >> 4;
    int ln   = lane & 15;

    __shared__ __hip_bfloat16 As[2][128 * 32];   // 2 x 8 KB
    __shared__ __hip_bfloat16 Bs[2][64 * 32];    // 2 x 4 KB
    __shared__ float s_out[16 * 132];            // epilogue transpose

    int lr  = lane >> 2;                      // 0..15
    int swz = (lane & 3) ^ (lr & 3);          // global k-chunk this lane fetches
    const __hip_bfloat16* gA0 = A + (size_t)(mt * 128 + w * 32 + lr) * CK + swz * 8;
    const __hip_bfloat16* gA1 = gA0 + (size_t)16 * CK;
    const __hip_bfloat16* gB  = Wbf + (size_t)(nt * 64 + w * 16 + lr) * CK + swz * 8;
    int lofA = (w * 32) * 32;                 // wave-uniform LDS offsets
    int lofB = (w * 16) * 32;

    floatx4 acc[2][4];
#pragma unroll
    for (int mi = 0; mi < 2; ++mi)
#pragma unroll
        for (int ns = 0; ns < 4; ++ns) acc[mi][ns] = (floatx4){0.f, 0.f, 0.f, 0.f};

    int sA = quad ^ (ln & 3);                 // swizzled read chunk

    // prologue: stage kt=0 into buffer 0
    gll16(gA0, &As[0][lofA]);
    gll16(gA1, &As[0][lofA + 16 * 32]);
    gll16(gB,  &Bs[0][lofB]);

    for (int kt = 0; kt < 72; ++kt) {
        int cur = kt & 1;
        int nxt = cur ^ 1;
        __syncthreads();                      // buf[cur] staging complete
        if (kt + 1 < 72) {                    // prefetch kt+1 (overlaps MFMA)
            int ko = (kt + 1) * 32;
            gll16(gA0 + ko, &As[nxt][lofA]);
            gll16(gA1 + ko, &As[nxt][lofA + 16 * 32]);
            gll16(gB  + ko, &Bs[nxt][lofB]);
        }
        shortx8 a0 = *(const shortx8*)&As[cur][(w * 32 + ln) * 32 + sA * 8];
        shortx8 a1 = *(const shortx8*)&As[cur][(w * 32 + 16 + ln) * 32 + sA * 8];
#pragma unroll
        for (int ns = 0; ns < 4; ++ns) {
            shortx8 bfr = *(const shortx8*)&Bs[cur][(ns * 16 + ln) * 32 + sA * 8];
            acc[0][ns] = __builtin_amdgcn_mfma_f32_16x16x32_bf16(a0, bfr, acc[0][ns], 0, 0, 0);
            acc[1][ns] = __builtin_amdgcn_mfma_f32_16x16x32_bf16(a1, bfr, acc[1][ns], 0, 0, 0);
        }
    }

    // ---- epilogue: transpose through LDS, coalesced NCHW stores ----
    int bb = mt >> 5;                   // batch
    int hwbase = (mt & 31) * 128;       // 128 contiguous hw pixels
#pragma unroll
    for (int ns = 0; ns < 4; ++ns) {
        __syncthreads();
#pragma unroll
        for (int mi = 0; mi < 2; ++mi) {
            floatx4 v = acc[mi][ns];
            *(floatx4*)&s_out[ln * 132 + w * 32 + mi * 16 + quad * 4] = v;
        }
        __syncthreads();
#pragma unroll
        for (int it = 0; it < 2; ++it) {
            int id = it * 256 + t;          // 0..511
            int co_l = id >> 5;             // 0..15
            int mch  = id & 31;             // 0..31 (4 floats each)
            floatx4 v = *(const floatx4*)&s_out[co_l * 132 + mch * 4];
            int co = nt * 64 + ns * 16 + co_l;
            *(floatx4*)&out[((size_t)(bb * COo + co) << 12) + hwbase + mch * 4] = v;
        }
    }
}

// ---------------------------------------------------------------------------
extern "C" void kernel_launch(void* const* d_in, const int* in_sizes, int n_in,
                              void* d_out, int out_size, void* d_ws, size_t ws_size,
                              hipStream_t stream)
{
    const float* x     = (const float*)d_in[0];
    const float* resid = (const float*)d_in[1];
    const float* off_w = (const float*)d_in[2];
    const float* off_b = (const float*)d_in[3];
    const float* mod_w = (const float*)d_in[4];
    const float* mod_b = (const float*)d_in[5];
    const float* reg_w = (const float*)d_in[6];
    float* out = (float*)d_out;

    float* ws = (float*)d_ws;
    _Float16* Pbuf       = (_Float16*)(ws + O_P);
    __hip_bfloat16* Wbf  = (__hip_bfloat16*)(ws + O_WBF);
    __hip_bfloat16* Wpk  = (__hip_bfloat16*)(ws + O_WPK);
    __hip_bfloat16* Abuf = (__hip_bfloat16*)(ws + O_A);

    pack_kernel<<<(CK * COo + 255) / 256, 256, 0, stream>>>(reg_w, off_w, mod_w, Wbf, Wpk);

    convA_kernel<<<512, 256, 0, stream>>>(x, resid, Wpk, Pbuf);

    gather_kernel<<<BB * HH * 16, 256, 0, stream>>>(x, Pbuf, off_b, mod_b, Abuf);

    gemm_kernel<<<64 * 4, 256, 0, stream>>>(Abuf, Wbf, out);
}

// Round 6
// 201.949 us; speedup vs baseline: 1.1917x; 1.1917x over previous
//
#include <hip/hip_runtime.h>
#include <hip/hip_bf16.h>
#include <math.h>

// Problem constants (B=2, C=256, H=W=64, Co=256, 3x3, stride1, pad1)
#define BB 2
#define CC 256
#define HH 64
#define WW 64
#define COo 256
#define HWs 4096
#define K2 9
#define CK 2304   // C*9

typedef __attribute__((ext_vector_type(4))) float floatx4;
typedef __attribute__((ext_vector_type(8))) short shortx8;   // 8 bf16 = 4 VGPRs

// ---- workspace layout (float units) ----
#define O_OFF   0          // final offset (bias applied)  B*18*4096 = 147456 f
#define O_MASK  147456     // final modulator (sigmoid'd)  B*9*4096  =  73728 f
#define O_WBF   221184     // reg_w bf16 [co][ck] = 589824 bf16 = 294912 f
#define O_WPK   516096     // convA weights [g2][kc8][tap9][nf2][lane][8] = 147456 bf16
#define O_A     589824     // A matrix bf16 [pix 8192][ck 2304] = 9437184 f
// P (convA fp16 partials, [kc8][b2][pix4096][27] = 1769472 halves) ALIASES the
// head of O_A: P is dead after reduce_kernel, before gather writes A.
// total = 10,027,008 floats = 40.1 MB (validated budget)

__device__ __forceinline__ void gll16(const __hip_bfloat16* g, __hip_bfloat16* l) {
    __builtin_amdgcn_global_load_lds(
        (const __attribute__((address_space(1))) unsigned int*)g,
        (__attribute__((address_space(3))) unsigned int*)l, 16, 0, 0);
}

__device__ __forceinline__ short f2bf(float v) {
    __hip_bfloat16 h = __float2bfloat16(v);
    return *reinterpret_cast<short*>(&h);
}

// ---------------------------------------------------------------------------
// K0: pack weights.
//  Wbf[co*2304+ck] = bf16(reg_w) (cast-copy, natural layout)
//  Wpk: convA weights: [g 2][kc 8][tap 9][nf 2][lane 64][j 8]
//   c = kc*32 + (lane>>4)*8 + j, n = nf*16 + (lane&15)
//   g=0: n<18 -> off_w[n][c][tap]; g=1: n<9 -> mod_w[n][c][tap]; else 0
// ---------------------------------------------------------------------------
__global__ __launch_bounds__(256) void pack_kernel(
    const float* __restrict__ reg_w,
    const float* __restrict__ off_w,
    const float* __restrict__ mod_w,
    __hip_bfloat16* __restrict__ Wbf,
    __hip_bfloat16* __restrict__ Wpk)
{
    int idx = blockIdx.x * 256 + threadIdx.x;      // grid covers CK*COo = 589824
    if (idx < CK * COo) {
        Wbf[idx] = __float2bfloat16(reg_w[idx]);
    }
    if (idx < 147456) {
        int g    = idx / 73728;
        int rem  = idx % 73728;
        int kc   = rem / 9216;
        int r2   = rem % 9216;
        int tap  = r2 / 1024;
        int r3   = r2 & 1023;
        int nf   = r3 >> 9;
        int r4   = r3 & 511;
        int lane = r4 >> 3;
        int j    = r4 & 7;
        int c    = kc * 32 + (lane >> 4) * 8 + j;
        int n    = nf * 16 + (lane & 15);
        float v = 0.f;
        if (g == 0) { if (n < 18) v = off_w[((size_t)n * CC + c) * 9 + tap]; }
        else        { if (n < 9)  v = mod_w[((size_t)n * CC + c) * 9 + tap]; }
        Wpk[idx] = __float2bfloat16(v);
    }
}

// ---------------------------------------------------------------------------
// K1: offset + modulator convs via MFMA. grid = 256: (b2,g2,kc8,rt8).
// Block = 8 rows x 64 cols (512 pixels) x 32 input channels. Weight slice
// 18 KB + x-tile 40 KB = 58 KB LDS -> 2 blocks/CU. fp16 partials to P[kc].
// ---------------------------------------------------------------------------
__global__ __launch_bounds__(256) void convA_kernel(
    const float* __restrict__ x,
    const float* __restrict__ residual,
    const __hip_bfloat16* __restrict__ Wpk,
    _Float16* __restrict__ P)
{
    int blk = blockIdx.x;
    int rt = blk & 7;
    int kc = (blk >> 3) & 7;
    int g  = (blk >> 6) & 1;
    int b  = blk >> 7;
    int t = threadIdx.x;
    int lane = t & 63;
    int w = t >> 6;
    int ln = lane & 15;
    int quad = lane >> 4;

    __shared__ __hip_bfloat16 Xs[640 * 32];   // 10 rows x 64 cols x 32 ch (40 KB)
    __shared__ __hip_bfloat16 Wl[9216];       // weight slice (18 KB)

    const float* src = (g ? x : residual) + ((size_t)b * CC + kc * 32) * HWs;
    const __hip_bfloat16* wsrc = Wpk + (size_t)(g * 8 + kc) * 9216;

    // weight staging: 1152 16B chunks via global_load_lds
#pragma unroll
    for (int i = 0; i < 4; ++i) {
        int cid = i * 256 + t;
        gll16(wsrc + cid * 8, &Wl[cid * 8]);
    }
    if (t < 128) {
        int cid = 1024 + t;
        gll16(wsrc + cid * 8, &Wl[cid * 8]);
    }

    // x-tile staging: rows rt*8-1 .. rt*8+8 (zero-padded), swizzled c-chunks
    int col = t & 63;
    int q = t >> 6;
#pragma unroll
    for (int i = 0; i < 10; ++i) {
        int p = q * 10 + i;            // 0..39
        int row = p >> 2;              // 0..9
        int cgp = p & 3;               // c-chunk of 8
        int rimg = rt * 8 + row - 1;
        bool rv = (rimg >= 0) && (rimg < HH);
        const float* sp = src + (size_t)(cgp * 8) * HWs + rimg * WW + col;
        shortx8 pk;
#pragma unroll
        for (int jc = 0; jc < 8; ++jc)
            pk[jc] = f2bf(rv ? sp[(size_t)jc * HWs] : 0.f);
        int colIdx = row * 64 + col;
        int pos = cgp ^ (colIdx & 3);
        *(shortx8*)&Xs[colIdx * 32 + pos * 8] = pk;
    }
    __syncthreads();                   // drains ds_writes + weight DMA

    floatx4 acc[8][2];
#pragma unroll
    for (int mf = 0; mf < 8; ++mf) {
        acc[mf][0] = (floatx4){0.f, 0.f, 0.f, 0.f};
        acc[mf][1] = (floatx4){0.f, 0.f, 0.f, 0.f};
    }

    // wave w owns pixels [w*128, (w+1)*128) = rows 2w, 2w+1 of the 8-row tile
#pragma unroll
    for (int tap = 0; tap < 9; ++tap) {
        int ky = tap / 3;
        int kx = tap % 3;
        const __hip_bfloat16* wp = &Wl[((tap * 2) * 64 + lane) * 8];
        shortx8 b0 = *(const shortx8*)wp;
        shortx8 b1 = *(const shortx8*)(wp + 512);
#pragma unroll
        for (int mf = 0; mf < 8; ++mf) {
            int p = (w * 8 + mf) * 16 + ln;
            int row_local = p >> 6;
            int colp = p & 63;
            int colA = colp + kx - 1;
            bool cv = (colA >= 0) && (colA < WW);
            int colC = cv ? colA : 0;
            int colIdx = (row_local + ky) * 64 + colC;
            int pos = quad ^ (colIdx & 3);
            shortx8 afr = *(const shortx8*)&Xs[colIdx * 32 + pos * 8];
            if (!cv) {
                shortx8 zf = {0,0,0,0,0,0,0,0};
                afr = zf;
            }
            acc[mf][0] = __builtin_amdgcn_mfma_f32_16x16x32_bf16(afr, b0, acc[mf][0], 0, 0, 0);
            acc[mf][1] = __builtin_amdgcn_mfma_f32_16x16x32_bf16(afr, b1, acc[mf][1], 0, 0, 0);
        }
    }

    // epilogue: C/D col=lane&15 (=n), row=quad*4+reg (=pixel within frag)
#pragma unroll
    for (int nf = 0; nf < 2; ++nf) {
        int n = nf * 16 + ln;
        bool valid = g ? (n < 9) : (n < 18);
        int n_eff = g ? (18 + n) : n;
        if (valid) {
#pragma unroll
            for (int mf = 0; mf < 8; ++mf) {
#pragma unroll
                for (int i2 = 0; i2 < 4; ++i2) {
                    int p = (w * 8 + mf) * 16 + quad * 4 + i2;
                    int pix = rt * 512 + p;
                    P[((size_t)(kc * 2 + b) * 4096 + pix) * 27 + n_eff] =
                        (_Float16)acc[mf][nf][i2];
                }
            }
        }
    }
}

// ---------------------------------------------------------------------------
// K1b: reduce 8 kc-partials + bias (+2*sigmoid for mask) -> final off/mask.
// grid = 864 (2*4096*27 items), fully coalesced.
// ---------------------------------------------------------------------------
__global__ __launch_bounds__(256) void reduce_kernel(
    const _Float16* __restrict__ P,
    const float* __restrict__ off_b,
    const float* __restrict__ mod_b,
    float* __restrict__ off_out,
    float* __restrict__ mask_out)
{
    int id = blockIdx.x * 256 + threadIdx.x;
    if (id >= 2 * 4096 * 27) return;
    int n = id % 27;
    int pb = id / 27;
    int pix = pb & 4095;
    int b = pb >> 12;
    float s = 0.f;
#pragma unroll
    for (int kcc = 0; kcc < 8; ++kcc)
        s += (float)P[((size_t)(kcc * 2 + b) * 4096 + pix) * 27 + n];
    if (n < 18) {
        off_out[((size_t)b * 18 + n) * 4096 + pix] = s + off_b[n];
    } else {
        float z = s + mod_b[n - 18];
        mask_out[((size_t)b * 9 + (n - 18)) * 4096 + pix] = 2.f / (1.f + __expf(-z));
    }
}

// ---------------------------------------------------------------------------
// K2: deformable gather -> bf16 A matrix [pix][ck].
// grid = B*H*16 (c-chunk of 16); block 256 = (wo 64) x (cg 4), 4 chan each.
// s_a transposed [ck][wo] (conflict-free lane-major writes); writeout
// transposes to coalesced 16B stores.
// ---------------------------------------------------------------------------
__global__ __launch_bounds__(256) void gather_kernel(
    const float* __restrict__ x,
    const float* __restrict__ off,
    const float* __restrict__ mask,
    __hip_bfloat16* __restrict__ A)
{
    int blk = blockIdx.x;            // ((b*64 + ho)*16 + cc)
    int cc = blk & 15;
    int ho = (blk >> 4) & 63;
    int b  = blk >> 10;
    int t  = threadIdx.x;
    int wo = t & 63;
    int cg = t >> 6;

    __shared__ int   s_idx[4][K2][64];
    __shared__ float s_w  [4][K2][64];
    __shared__ short s_a[144 * 66];   // [ck_local][wo], pitch 66

    // ---- bilinear precompute from final offset/mask ----
    for (int u = t; u < K2 * 64; u += 256) {
        int k = u >> 6;
        int wv = u & 63;
        float dy = off[((((size_t)b * 18 + 2 * k    ) * HH + ho) << 6) + wv];
        float dx = off[((((size_t)b * 18 + 2 * k + 1) * HH + ho) << 6) + wv];
        float m  = mask[((((size_t)b * 9 + k) * HH + ho) << 6) + wv];
        float py = (float)(ho - 1 + k / 3) + dy;
        float px = (float)(wv - 1 + k % 3) + dx;
        float y0f = floorf(py), x0f = floorf(px);
        float wy1 = py - y0f, wx1 = px - x0f;
        float wy0 = 1.f - wy1, wx0 = 1.f - wx1;
        int y0 = (int)y0f, x0 = (int)x0f;
#pragma unroll
        for (int j = 0; j < 4; ++j) {
            int yy = y0 + (j >> 1);
            int xx = x0 + (j & 1);
            float wj = ((j == 0) ? wy0 * wx0 :
                        (j == 1) ? wy0 * wx1 :
                        (j == 2) ? wy1 * wx0 : wy1 * wx1) * m;
            bool valid = (yy >= 0) && (yy < HH) && (xx >= 0) && (xx < WW);
            s_idx[j][k][wv] = valid ? (yy * WW + xx) : 0;
            s_w  [j][k][wv] = valid ? wj : 0.f;
        }
    }
    __syncthreads();

    // ---- gather: k-outer, 4 channels inner; transposed s_a writes ----
    const float* xb = x + ((size_t)b * CC + cc * 16) * HWs;
#pragma unroll
    for (int k = 0; k < K2; ++k) {
        int   i0 = s_idx[0][k][wo], i1 = s_idx[1][k][wo];
        int   i2 = s_idx[2][k][wo], i3 = s_idx[3][k][wo];
        float w0 = s_w[0][k][wo], w1 = s_w[1][k][wo];
        float w2 = s_w[2][k][wo], w3 = s_w[3][k][wo];
#pragma unroll
        for (int j = 0; j < 4; ++j) {
            int cl = cg * 4 + j;
            const float* xc = xb + (size_t)cl * HWs;
            float v = w0 * xc[i0] + w1 * xc[i1] + w2 * xc[i2] + w3 * xc[i3];
            s_a[(cl * 9 + k) * 66 + wo] = f2bf(v);
        }
    }
    __syncthreads();

    // ---- writeout: transpose from s_a, 16B coalesced global stores ----
    int pixbase = (b * 64 + ho) * 64;
    for (int id = t; id < 1152; id += 256) {     // 64 rows x 18 chunks
        int rr  = id / 18;
        int ch8 = id % 18;
        shortx8 pk;
#pragma unroll
        for (int jj = 0; jj < 8; ++jj)
            pk[jj] = s_a[(ch8 * 8 + jj) * 66 + rr];
        *(shortx8*)(A + (size_t)(pixbase + rr) * CK + cc * 144 + ch8 * 8) = pk;
    }
}

// ---------------------------------------------------------------------------
// K3: bf16 MFMA GEMM  C[8192][256] = A[8192][2304] x Wbf^T, out NCHW.
// 64M x 64N tiles, BK=32, grid = 128x4 = 512 blocks (2/CU: co-resident
// blocks hide each other's barrier-drain DMA stalls). Double-buffered
// global_load_lds staging with XOR k-chunk swizzle on the global address.
// ---------------------------------------------------------------------------
__global__ __launch_bounds__(256) void gemm_kernel(
    const __hip_bfloat16* __restrict__ A,
    const __hip_bfloat16* __restrict__ Wbf,
    float* __restrict__ out)
{
    int blk = blockIdx.x;
    int mt = blk >> 2;          // 0..127: pix base mt*64
    int nt = blk & 3;           // co base nt*64
    int t  = threadIdx.x;
    int lane = t & 63;
    int w    = t >> 6;
    int quad = lane >> 4;
    int ln   = lane & 15;

    __shared__ __hip_bfloat16 As[2][64 * 32];   // 2 x 4 KB
    __shared__ __hip_bfloat16 Bs[2][64 * 32];   // 2 x 4 KB
    __shared__ float s_out[16 * 68];            // epilogue transpose

    int lr  = lane >> 2;                      // 0..15
    int swz = (lane & 3) ^ (lr & 3);          // global k-chunk this lane fetches
    const __hip_bfloat16* gA = A   + (size_t)(mt * 64 + w * 16 + lr) * CK + swz * 8;
    const __hip_bfloat16* gB = Wbf + (size_t)(nt * 64 + w * 16 + lr) * CK + swz * 8;
    int lof = (w * 16) * 32;                  // wave-uniform LDS offset

    floatx4 acc[4];
#pragma unroll
    for (int ns = 0; ns < 4; ++ns) acc[ns] = (floatx4){0.f, 0.f, 0.f, 0.f};

    int sA = quad ^ (ln & 3);                 // swizzled read chunk

    gll16(gA, &As[0][lof]);
    gll16(gB, &Bs[0][lof]);

    for (int kt = 0; kt < 72; ++kt) {
        int cur = kt & 1;
        int nxt = cur ^ 1;
        __syncthreads();                      // buf[cur] staging complete
        if (kt + 1 < 72) {
            int ko = (kt + 1) * 32;
            gll16(gA + ko, &As[nxt][lof]);
            gll16(gB + ko, &Bs[nxt][lof]);
        }
        shortx8 a0 = *(const shortx8*)&As[cur][(w * 16 + ln) * 32 + sA * 8];
#pragma unroll
        for (int ns = 0; ns < 4; ++ns) {
            shortx8 bfr = *(const shortx8*)&Bs[cur][(ns * 16 + ln) * 32 + sA * 8];
            acc[ns] = __builtin_amdgcn_mfma_f32_16x16x32_bf16(a0, bfr, acc[ns], 0, 0, 0);
        }
    }

    // ---- epilogue: transpose through LDS, coalesced NCHW stores ----
    int bb = mt >> 6;                   // batch
    int hwbase = (mt & 63) * 64;        // 64 contiguous hw pixels
#pragma unroll
    for (int ns = 0; ns < 4; ++ns) {
        __syncthreads();
        *(floatx4*)&s_out[ln * 68 + w * 16 + quad * 4] = acc[ns];
        __syncthreads();
        int co_l = t >> 4;              // 0..15
        int mch  = t & 15;              // 0..15 (4 floats each)
        floatx4 v = *(const floatx4*)&s_out[co_l * 68 + mch * 4];
        int co = nt * 64 + ns * 16 + co_l;
        *(floatx4*)&out[((size_t)(bb * COo + co) << 12) + hwbase + mch * 4] = v;
    }
}

// ---------------------------------------------------------------------------
extern "C" void kernel_launch(void* const* d_in, const int* in_sizes, int n_in,
                              void* d_out, int out_size, void* d_ws, size_t ws_size,
                              hipStream_t stream)
{
    const float* x     = (const float*)d_in[0];
    const float* resid = (const float*)d_in[1];
    const float* off_w = (const float*)d_in[2];
    const float* off_b = (const float*)d_in[3];
    const float* mod_w = (const float*)d_in[4];
    const float* mod_b = (const float*)d_in[5];
    const float* reg_w = (const float*)d_in[6];
    float* out = (float*)d_out;

    float* ws = (float*)d_ws;
    float* off_buf   = ws + O_OFF;
    float* mask_buf  = ws + O_MASK;
    __hip_bfloat16* Wbf  = (__hip_bfloat16*)(ws + O_WBF);
    __hip_bfloat16* Wpk  = (__hip_bfloat16*)(ws + O_WPK);
    __hip_bfloat16* Abuf = (__hip_bfloat16*)(ws + O_A);
    _Float16* Pbuf       = (_Float16*)(ws + O_A);   // aliases A head (dead before gather)

    pack_kernel<<<(CK * COo + 255) / 256, 256, 0, stream>>>(reg_w, off_w, mod_w, Wbf, Wpk);

    convA_kernel<<<256, 256, 0, stream>>>(x, resid, Wpk, Pbuf);

    reduce_kernel<<<864, 256, 0, stream>>>(Pbuf, off_b, mod_b, off_buf, mask_buf);

    gather_kernel<<<BB * HH * 16, 256, 0, stream>>>(x, off_buf, mask_buf, Abuf);

    gemm_kernel<<<512, 256, 0, stream>>>(Abuf, Wbf, out);
}